// Round 7
// baseline (197.389 us; speedup 1.0000x reference)
//
#include <hip/hip_runtime.h>
#include <hip/hip_bf16.h>

// ---------------------------------------------------------------------------
// KeypointWeighting R7: counted-vmcnt software pipeline (T3+T4) for the GEMM.
//   B (weights): 3-deep LDS ring, staged 2 K-steps ahead via global_load_lds.
//   A (pf):      f32->regs 2 steps ahead, cvt->bf16 LDS 2-buf, post-barrier.
//   Per step: s_waitcnt vmcnt(4); lgkmcnt(0); s_barrier; stage(t+2); compute.
//   Never drains vmcnt in-loop (only final iteration).
// De-fused pipeline: convert_w -> gemm -> scan -> scatter -> fill_tail.
// dims: B=8 N=16384 C=640 H=256 O=128, 2048 tiles of 64 rows.
// ---------------------------------------------------------------------------

typedef __attribute__((ext_vector_type(8))) short short8v;
typedef __attribute__((ext_vector_type(4))) float f32x4;

#define M_TOTAL 131072
#define C_DIM 640
#define H_DIM 256
#define O_DIM 128
#define NCOMB 384
#define TM 64
#define KSTEPS 20
#define N_PTS 16384
#define TILES_PER_B 256
#define NTILES 2048
#define THRL -0.4054651081f   // log(0.4/0.6)
#define FIX_MARGIN 0.03f

#define OUT_COORD_OFF 16777216
#define OUT_MASK_OFF  17170432

// ws layout (bytes)
#define WT_OFF     0u
#define TMASK_OFF  491520u     // u64 [2048]
#define TAGG_OFF   507904u     // i32 [2048]
#define TEXCL_OFF  516096u     // i32 [2048]
#define COUNTS_OFF 524288u     // i32 [8]
#define G_OFF      1572864u    // f32 [131072][128]

#define VMCNT(n) asm volatile("s_waitcnt vmcnt(" #n ")" ::: "memory")
#define LGKMCNT0 asm volatile("s_waitcnt lgkmcnt(0)" ::: "memory")

// B swizzle (involution) — verified 0 bank conflicts in R4-R6.
__device__ __forceinline__ int swzB(int u) { return u ^ ((u >> 3) & 7); }

__device__ __forceinline__ void glds16(const void* g, void* l) {
  const __attribute__((address_space(1))) unsigned int* gp =
      reinterpret_cast<const __attribute__((address_space(1))) unsigned int*>(
          reinterpret_cast<uintptr_t>(g));
  __attribute__((address_space(3))) unsigned int* lp =
      reinterpret_cast<__attribute__((address_space(3))) unsigned int*>(
          reinterpret_cast<uintptr_t>(l));
  __builtin_amdgcn_global_load_lds(gp, lp, 16, 0, 0);
}

__device__ __forceinline__ unsigned int f2bf_bits(float f) {
  unsigned int u = __builtin_bit_cast(unsigned int, f);
  return (u + 0x7fffu + ((u >> 16) & 1u)) >> 16;
}
__device__ __forceinline__ unsigned int pack_bf2(float lo, float hi) {
  return f2bf_bits(lo) | (f2bf_bits(hi) << 16);
}

// K0: weights -> bf16 staged order (slot r holds logical granule swzB(r))
__global__ __launch_bounds__(256) void convert_w(const float* __restrict__ w1,
                                                 const float* __restrict__ wo,
                                                 unsigned short* __restrict__ Wt2) {
  int o = blockIdx.x * 256 + threadIdx.x;  // 960 x 256 = 245760
  if (o < NCOMB * C_DIM) {
    int e = o & 7;
    int chunk = o >> 3;
    int ks = chunk / 1536;
    int r = chunk - ks * 1536;
    int u = swzB(r);
    int n = u >> 2, kg = u & 3;
    int k = ks * 32 + kg * 8 + e;
    float v = (n < H_DIM) ? w1[k * H_DIM + n] : wo[k * O_DIM + (n - H_DIM)];
    Wt2[o] = (unsigned short)f2bf_bits(v);
  }
}

// K1: pipelined GEMM + scores (+fp32 fixup) + selmask + scaled G rows.
__global__ __launch_bounds__(512, 4) void gemm_fused(
    const float* __restrict__ pf, const unsigned short* __restrict__ Wt2,
    const float* __restrict__ w1, const float* __restrict__ b1,
    const float* __restrict__ w2, const float* __restrict__ b2,
    const float* __restrict__ bo, unsigned long long* __restrict__ tmask,
    int* __restrict__ tagg, float* __restrict__ G) {
  // 80 KB total -> 2 blocks/CU. Epilogue arrays aliased into staging buffers.
  __shared__ __align__(16) unsigned short As[2][2048];   // 2 x 4 KB bf16 A
  __shared__ __align__(16) unsigned short Bs[3][12288];  // 3 x 24 KB bf16 B

  const int tid = threadIdx.x;
  const int lane = tid & 63;
  const int wv = tid >> 6;
  const int q = lane & 15;
  const int p = lane >> 4;
  const int tile = blockIdx.x;
  const int m0 = tile * TM;

  f32x4 acc[3][4];
#pragma unroll
  for (int i = 0; i < 3; ++i)
#pragma unroll
    for (int rt = 0; rt < 4; ++rt) acc[i][rt] = (f32x4){0.f, 0.f, 0.f, 0.f};

  // A staging: thread -> pf[row = tid>>3][k0 + (tid&7)*4], 4 floats -> 8 B bf16.
  const float* asrc = pf + (size_t)(m0 + (tid >> 3)) * C_DIM + (tid & 7) * 4;
  const int aphys = ((tid >> 1) ^ ((tid >> 4) & 3)) * 8 + (tid & 1) * 4;  // ushort idx
  const int aswz = (q >> 1) & 3;  // read-side swizzle constant

  // ---- prologue: stage B(0),B(1); pf(0),pf(1) to regs; A(0) to LDS
  float4 Rcur, Rnext;
  {
    Rcur = *(const float4*)(asrc);              // pf(0)
#pragma unroll
    for (int u = 0; u < 3; ++u)
      glds16(Wt2 + (size_t)(u * 512 + tid) * 8, &Bs[0][(u * 512 + tid) * 8]);
    Rnext = *(const float4*)(asrc + 32);        // pf(1)
#pragma unroll
    for (int u = 0; u < 3; ++u)
      glds16(Wt2 + (size_t)(1536 + u * 512 + tid) * 8, &Bs[1][(u * 512 + tid) * 8]);
    // cvt pf(0) -> A buf0 (compiler inserts the minimal vmcnt for Rcur)
    *(uint2*)&As[0][aphys] = make_uint2(pack_bf2(Rcur.x, Rcur.y), pack_bf2(Rcur.z, Rcur.w));
    Rcur = Rnext;
  }

  // ---- main loop: 1 barrier/step, vmcnt never drained until the last step
#pragma unroll
  for (int t = 0; t < KSTEPS; ++t) {
    if (t < KSTEPS - 1) { VMCNT(4); } else { VMCNT(0); }
    LGKMCNT0;
    __builtin_amdgcn_s_barrier();
    __builtin_amdgcn_sched_barrier(0);
    if (t + 2 < KSTEPS) {
      Rnext = *(const float4*)(asrc + (t + 2) * 32);
#pragma unroll
      for (int u = 0; u < 3; ++u)
        glds16(Wt2 + (size_t)((t + 2) * 1536 + u * 512 + tid) * 8,
               &Bs[(t + 2) % 3][(u * 512 + tid) * 8]);
      __builtin_amdgcn_sched_barrier(0);
    }
    if (t + 1 < KSTEPS) {  // cvt pf(t+1) -> A buf^1 (post-barrier: WAR-safe)
      *(uint2*)&As[(t + 1) & 1][aphys] =
          make_uint2(pack_bf2(Rcur.x, Rcur.y), pack_bf2(Rcur.z, Rcur.w));
      Rcur = Rnext;
    }
    // compute on A[t&1], B[t%3]
    short8v af[4];
#pragma unroll
    for (int rt = 0; rt < 4; ++rt)
      af[rt] = *(const short8v*)&As[t & 1][((rt * 64 + q * 4 + p) ^ aswz) * 8];
    __builtin_amdgcn_s_setprio(1);
#pragma unroll
    for (int i = 0; i < 3; ++i) {
      const int ub = (((wv + 8 * i) * 16 + q) << 2) + p;
      short8v bfv = *(const short8v*)&Bs[t % 3][swzB(ub) * 8];
#pragma unroll
      for (int rt = 0; rt < 4; ++rt)
        acc[i][rt] = __builtin_amdgcn_mfma_f32_16x16x32_bf16(af[rt], bfv, acc[i][rt], 0, 0, 0);
    }
    __builtin_amdgcn_s_setprio(0);
  }
  __syncthreads();  // full drain once; staging buffers become epilogue scratch

  // epilogue scratch aliases
  float* lpart = (float*)&As[0][0];                 // [8][64] = 8 KB = all of As
  float* llog = (float*)&Bs[0][0];                  // 64
  float* srow = llog + 64;                          // 64
  float* fsum = srow + 64;                          // 4
  unsigned long long* s_fixmask = (unsigned long long*)(fsum + 4);

  // ---- logits over col-tiles i=0,1 (cols 0..255)
  float w2v[2], b1v[2];
#pragma unroll
  for (int i = 0; i < 2; ++i) {
    int col = (wv + 8 * i) * 16 + q;
    w2v[i] = w2[col];
    b1v[i] = b1[col];
  }
#pragma unroll
  for (int rt = 0; rt < 4; ++rt) {
    float pr[4] = {0.f, 0.f, 0.f, 0.f};
#pragma unroll
    for (int i = 0; i < 2; ++i)
#pragma unroll
      for (int r = 0; r < 4; ++r)
        pr[r] += fmaxf(acc[i][rt][r] + b1v[i], 0.f) * w2v[i];
#pragma unroll
    for (int mk = 1; mk < 16; mk <<= 1)
#pragma unroll
      for (int r = 0; r < 4; ++r) pr[r] += __shfl_xor(pr[r], mk);
    if (q == 0)
#pragma unroll
      for (int r = 0; r < 4; ++r) lpart[wv * 64 + rt * 16 + p * 4 + r] = pr[r];
  }
  __syncthreads();

  bool nf = false;
  if (wv == 0) {
    float lg = b2[0];
#pragma unroll
    for (int w = 0; w < 8; ++w) lg += lpart[w * 64 + tid];
    llog[tid] = lg;
    nf = fabsf(lg - THRL) < FIX_MARGIN;
  }
  unsigned long long fm = __ballot(nf);
  if (tid == 0) *s_fixmask = fm;
  __syncthreads();

  // ---- exact fp32 recompute of borderline rows (rare)
  unsigned long long fixmask = *s_fixmask;
  while (fixmask) {
    int row = __ffsll(fixmask) - 1;
    fixmask &= fixmask - 1;
    if (tid < 256) {
      const float* prow = pf + (size_t)(m0 + row) * C_DIM;
      float a0 = 0.f, a1 = 0.f;
      for (int c = 0; c < C_DIM; c += 2) {
        a0 = fmaf(prow[c], w1[(size_t)c * H_DIM + tid], a0);
        a1 = fmaf(prow[c + 1], w1[(size_t)(c + 1) * H_DIM + tid], a1);
      }
      float v = fmaxf(a0 + a1 + b1[tid], 0.f) * w2[tid];
#pragma unroll
      for (int mk = 1; mk < 64; mk <<= 1) v += __shfl_xor(v, mk);
      if (lane == 0) fsum[wv] = v;
    }
    __syncthreads();
    if (tid == 0)
      llog[row] = fsum[0] + fsum[1] + fsum[2] + fsum[3] + b2[0];
    __syncthreads();
  }

  // ---- selection mask + aggregate + scores
  bool sel = false;
  float flog = 0.f;
  if (wv == 0) {
    flog = llog[tid];
    sel = flog > THRL;
  }
  unsigned long long selmask = __ballot(sel);
  if (wv == 0) {
    srow[tid] = 1.f / (1.f + expf(-flog));
    if (tid == 0) {
      tmask[tile] = selmask;
      tagg[tile] = __popcll(selmask);
    }
  }
  __syncthreads();

  // ---- scaled feature rows: G[m] = score*(pf@wo)+bo (col-tile i=2)
  {
    const int gcol = wv * 16 + q;
    const float bov = bo[gcol];
#pragma unroll
    for (int rt = 0; rt < 4; ++rt)
#pragma unroll
      for (int r = 0; r < 4; ++r) {
        int row = rt * 16 + p * 4 + r;
        G[(size_t)(m0 + row) * O_DIM + gcol] = fmaf(acc[2][rt][r], srow[row], bov);
      }
  }
}

// K2: per-batch exclusive scan of 256 tile aggregates. grid 8, block 256.
__global__ __launch_bounds__(256) void scan_tiles(const int* __restrict__ tagg,
                                                  int* __restrict__ texcl,
                                                  int* __restrict__ counts) {
  __shared__ int wsum[4];
  const int c = blockIdx.x, t = threadIdx.x;
  const int lane = t & 63, w = t >> 6;
  int v = tagg[c * 256 + t];
  int inc = v;
#pragma unroll
  for (int d = 1; d < 64; d <<= 1) {
    int n = __shfl_up(inc, d);
    if (lane >= d) inc += n;
  }
  if (lane == 63) wsum[w] = inc;
  __syncthreads();
  int base = 0;
#pragma unroll
  for (int ww = 0; ww < 4; ++ww)
    if (ww < w) base += wsum[ww];
  texcl[c * 256 + t] = base + inc - v;
  if (t == 255) counts[c] = base + inc;
}

// K3: compact selected rows. grid 2048, block 512 (wave wv: rows wv*8..+7)
__global__ __launch_bounds__(512) void scatter(
    const float* __restrict__ G, const unsigned long long* __restrict__ tmask,
    const int* __restrict__ texcl, const float* __restrict__ pc,
    float* __restrict__ out) {
  const int tile = blockIdx.x;
  const int tid = threadIdx.x;
  const int lane = tid & 63;
  const int wv = tid >> 6;
  const unsigned long long mask = tmask[tile];
  const int base = (tile >> 8) * N_PTS + texcl[tile];
  const int m0 = tile * TM;
#pragma unroll
  for (int j = 0; j < 8; ++j) {
    const int row = wv * 8 + j;
    if (!((mask >> row) & 1ull)) continue;
    const int dst = base + __popcll(mask & ((1ull << row) - 1ull));
    const int m = m0 + row;
    float2 g = *(const float2*)(G + (size_t)m * O_DIM + lane * 2);
    *(float2*)(out + (size_t)dst * O_DIM + lane * 2) = g;
    if (lane == 0) {
      float c0 = pc[m * 3], c1 = pc[m * 3 + 1], c2 = pc[m * 3 + 2];
      float* oc = out + OUT_COORD_OFF;
      oc[dst * 3] = c0; oc[dst * 3 + 1] = c1; oc[dst * 3 + 2] = c2;
      out[OUT_MASK_OFF + dst] = (c0 == 0.f || c1 == 0.f || c2 == 0.f) ? 1.f : 0.f;
    }
  }
}

// K4: zero-fill padding tail rows; mask=1 there
__global__ __launch_bounds__(256) void fill_tail(const int* __restrict__ counts,
                                                 float* __restrict__ out) {
  int m = blockIdx.x * 4 + (threadIdx.x >> 6);
  int lane = threadIdx.x & 63;
  int b = m >> 14, j = m & (N_PTS - 1);
  if (j < counts[b]) return;
  *(float2*)(out + (size_t)m * O_DIM + lane * 2) = make_float2(0.f, 0.f);
  if (lane == 0) {
    float* oc = out + OUT_COORD_OFF;
    oc[m * 3] = 0.f; oc[m * 3 + 1] = 0.f; oc[m * 3 + 2] = 0.f;
    out[OUT_MASK_OFF + m] = 1.f;
  }
}

extern "C" void kernel_launch(void* const* d_in, const int* in_sizes, int n_in,
                              void* d_out, int out_size, void* d_ws, size_t ws_size,
                              hipStream_t stream) {
  const float* pf = (const float*)d_in[0];
  const float* pc = (const float*)d_in[1];
  const float* w1 = (const float*)d_in[2];
  const float* b1 = (const float*)d_in[3];
  const float* w2 = (const float*)d_in[4];
  const float* b2 = (const float*)d_in[5];
  const float* wo = (const float*)d_in[6];
  const float* bo = (const float*)d_in[7];
  float* out = (float*)d_out;
  char* ws = (char*)d_ws;

  unsigned short* Wt2 = (unsigned short*)(ws + WT_OFF);
  unsigned long long* tmask = (unsigned long long*)(ws + TMASK_OFF);
  int* tagg = (int*)(ws + TAGG_OFF);
  int* texcl = (int*)(ws + TEXCL_OFF);
  int* counts = (int*)(ws + COUNTS_OFF);
  float* G = (float*)(ws + G_OFF);

  convert_w<<<960, 256, 0, stream>>>(w1, wo, Wt2);
  gemm_fused<<<NTILES, 512, 0, stream>>>(pf, Wt2, w1, b1, w2, b2, bo,
                                         tmask, tagg, G);
  scan_tiles<<<8, 256, 0, stream>>>(tagg, texcl, counts);
  scatter<<<NTILES, 512, 0, stream>>>(G, tmask, texcl, pc, out);
  fill_tail<<<M_TOTAL / 4, 256, 0, stream>>>(counts, out);
}

// Round 8
// 193.662 us; speedup vs baseline: 1.0192x; 1.0192x over previous
//
#include <hip/hip_runtime.h>
#include <hip/hip_bf16.h>

// ---------------------------------------------------------------------------
// KeypointWeighting R8: phase-split K-loop (T3 structure) on the R7 chassis.
// Per K-step (32 k), TWO phases, each: {ds_read ∥ stage-issue} -> barrier ->
// lgkmcnt(0) -> sched_barrier -> setprio+6 MFMA+setprio -> barrier.
// Counted vmcnt(4) once per step (ph1), drains only at tail.
// B: 3-deep LDS ring staged 2 steps ahead (global_load_lds).
// A: pf f32 -> regs (2 ahead) -> cvt -> bf16 LDS 2-buf.
// De-fused pipeline: convert_w -> gemm -> scan -> scatter -> fill_tail.
// ---------------------------------------------------------------------------

typedef __attribute__((ext_vector_type(8))) short short8v;
typedef __attribute__((ext_vector_type(4))) float f32x4;

#define M_TOTAL 131072
#define C_DIM 640
#define H_DIM 256
#define O_DIM 128
#define NCOMB 384
#define TM 64
#define KSTEPS 20
#define N_PTS 16384
#define TILES_PER_B 256
#define NTILES 2048
#define THRL -0.4054651081f   // log(0.4/0.6)
#define FIX_MARGIN 0.03f

#define OUT_COORD_OFF 16777216
#define OUT_MASK_OFF  17170432

// ws layout (bytes)
#define WT_OFF     0u
#define TMASK_OFF  491520u     // u64 [2048]
#define TAGG_OFF   507904u     // i32 [2048]
#define TEXCL_OFF  516096u     // i32 [2048]
#define COUNTS_OFF 524288u     // i32 [8]
#define G_OFF      1572864u    // f32 [131072][128]

#define VMCNT(n) asm volatile("s_waitcnt vmcnt(" #n ")" ::: "memory")
#define LGKMCNT0 asm volatile("s_waitcnt lgkmcnt(0)" ::: "memory")
#define SBAR __builtin_amdgcn_s_barrier()
#define SCHED0 __builtin_amdgcn_sched_barrier(0)

// B swizzle (involution) — measured 0 bank conflicts (R4/R5).
__device__ __forceinline__ int swzB(int u) { return u ^ ((u >> 3) & 7); }

__device__ __forceinline__ void glds16(const void* g, void* l) {
  const __attribute__((address_space(1))) unsigned int* gp =
      reinterpret_cast<const __attribute__((address_space(1))) unsigned int*>(
          reinterpret_cast<uintptr_t>(g));
  __attribute__((address_space(3))) unsigned int* lp =
      reinterpret_cast<__attribute__((address_space(3))) unsigned int*>(
          reinterpret_cast<uintptr_t>(l));
  __builtin_amdgcn_global_load_lds(gp, lp, 16, 0, 0);
}

__device__ __forceinline__ unsigned int f2bf_bits(float f) {
  unsigned int u = __builtin_bit_cast(unsigned int, f);
  return (u + 0x7fffu + ((u >> 16) & 1u)) >> 16;
}
__device__ __forceinline__ unsigned int pack_bf2(float lo, float hi) {
  return f2bf_bits(lo) | (f2bf_bits(hi) << 16);
}

// K0: weights -> bf16 staged order (slot r holds logical granule swzB(r))
__global__ __launch_bounds__(256) void convert_w(const float* __restrict__ w1,
                                                 const float* __restrict__ wo,
                                                 unsigned short* __restrict__ Wt2) {
  int o = blockIdx.x * 256 + threadIdx.x;  // 960 x 256 = 245760
  if (o < NCOMB * C_DIM) {
    int e = o & 7;
    int chunk = o >> 3;
    int ks = chunk / 1536;
    int r = chunk - ks * 1536;
    int u = swzB(r);
    int n = u >> 2, kg = u & 3;
    int k = ks * 32 + kg * 8 + e;
    float v = (n < H_DIM) ? w1[k * H_DIM + n] : wo[k * O_DIM + (n - H_DIM)];
    Wt2[o] = (unsigned short)f2bf_bits(v);
  }
}

// K1: phase-split pipelined GEMM + scores (+fp32 fixup) + selmask + G rows.
__global__ __launch_bounds__(512, 4) void gemm_fused(
    const float* __restrict__ pf, const unsigned short* __restrict__ Wt2,
    const float* __restrict__ w1, const float* __restrict__ b1,
    const float* __restrict__ w2, const float* __restrict__ b2,
    const float* __restrict__ bo, unsigned long long* __restrict__ tmask,
    int* __restrict__ tagg, float* __restrict__ G) {
  __shared__ __align__(16) unsigned short As[2][2048];   // 2 x 4 KB
  __shared__ __align__(16) unsigned short Bs[3][12288];  // 3 x 24 KB

  const int tid = threadIdx.x;
  const int lane = tid & 63;
  const int wv = tid >> 6;
  const int q = lane & 15;
  const int p = lane >> 4;
  const int tile = blockIdx.x;
  const int m0 = tile * TM;

  f32x4 acc[3][4];
#pragma unroll
  for (int i = 0; i < 3; ++i)
#pragma unroll
    for (int rt = 0; rt < 4; ++rt) acc[i][rt] = (f32x4){0.f, 0.f, 0.f, 0.f};

  // A staging: thread -> pf[row = tid>>3][k0 + (tid&7)*4], 4 floats -> 8 B bf16.
  const float* asrc = pf + (size_t)(m0 + (tid >> 3)) * C_DIM + (tid & 7) * 4;
  const int aphys = ((tid >> 1) ^ ((tid >> 4) & 3)) * 8 + (tid & 1) * 4;
  const int aswz = (q >> 1) & 3;

  // ---- prologue: B(0),B(1) staged; A(0) in LDS; pf(1) in regs
  float4 Rcur, Rnext;
  {
    float4 R0 = *(const float4*)(asrc);         // pf(0)
#pragma unroll
    for (int u = 0; u < 3; ++u)
      glds16(Wt2 + (size_t)(u * 512 + tid) * 8, &Bs[0][(u * 512 + tid) * 8]);
#pragma unroll
    for (int u = 0; u < 3; ++u)
      glds16(Wt2 + (size_t)(1536 + u * 512 + tid) * 8, &Bs[1][(u * 512 + tid) * 8]);
    Rcur = *(const float4*)(asrc + 32);          // pf(1)
    *(uint2*)&As[0][aphys] = make_uint2(pack_bf2(R0.x, R0.y), pack_bf2(R0.z, R0.w));
    LGKMCNT0;        // A(0) write drained
    VMCNT(4);        // B(0) landed (leaves B(1)+pf(1) in flight)
    SBAR;
  }

  // ---- main loop: 2 phases per K-step
#pragma unroll
  for (int t = 0; t < KSTEPS; ++t) {
    short8v af01[2], af23[2], bf[3];
    // ======== phase 0 ========
    // ds_read: af rt0,rt1 + all 3 B frags of this step
#pragma unroll
    for (int rt = 0; rt < 2; ++rt)
      af01[rt] = *(const short8v*)&As[t & 1][((rt * 64 + q * 4 + p) ^ aswz) * 8];
#pragma unroll
    for (int i = 0; i < 3; ++i) {
      const int ub = (((wv + 8 * i) * 16 + q) << 2) + p;
      bf[i] = *(const short8v*)&Bs[t % 3][swzB(ub) * 8];
    }
    // stage-issue for step t+2
    if (t + 2 < KSTEPS) {
      Rnext = *(const float4*)(asrc + (t + 2) * 32);
#pragma unroll
      for (int u = 0; u < 3; ++u)
        glds16(Wt2 + (size_t)((t + 2) * 1536 + u * 512 + tid) * 8,
               &Bs[(t + 2) % 3][(u * 512 + tid) * 8]);
    }
    SBAR;
    LGKMCNT0;
    SCHED0;
    __builtin_amdgcn_s_setprio(1);
#pragma unroll
    for (int i = 0; i < 3; ++i)
#pragma unroll
      for (int rt = 0; rt < 2; ++rt)
        acc[i][rt] = __builtin_amdgcn_mfma_f32_16x16x32_bf16(af01[rt], bf[i],
                                                             acc[i][rt], 0, 0, 0);
    __builtin_amdgcn_s_setprio(0);
    SBAR;
    // ======== phase 1 ========
#pragma unroll
    for (int rt = 2; rt < 4; ++rt)
      af23[rt - 2] = *(const short8v*)&As[t & 1][((rt * 64 + q * 4 + p) ^ aswz) * 8];
    if (t + 1 < KSTEPS) {  // cvt pf(t+1) -> A[(t+1)&1]
      *(uint2*)&As[(t + 1) & 1][aphys] =
          make_uint2(pack_bf2(Rcur.x, Rcur.y), pack_bf2(Rcur.z, Rcur.w));
      Rcur = Rnext;
    }
    LGKMCNT0;            // my ds_reads + A-write drained before signaling
    if (t + 2 < KSTEPS) { VMCNT(4); } else { VMCNT(0); }  // B(t+1) landed
    SBAR;
    SCHED0;
    __builtin_amdgcn_s_setprio(1);
#pragma unroll
    for (int i = 0; i < 3; ++i)
#pragma unroll
      for (int rt = 2; rt < 4; ++rt)
        acc[i][rt] = __builtin_amdgcn_mfma_f32_16x16x32_bf16(af23[rt - 2], bf[i],
                                                             acc[i][rt], 0, 0, 0);
    __builtin_amdgcn_s_setprio(0);
    SBAR;
  }
  __syncthreads();  // full drain; staging buffers become epilogue scratch

  // epilogue scratch aliases
  float* lpart = (float*)&As[0][0];                 // [8][64] = 2 KB
  float* llog = (float*)&Bs[0][0];                  // 64
  float* srow = llog + 64;                          // 64
  float* fsum = srow + 64;                          // 4
  unsigned long long* s_fixmask = (unsigned long long*)(fsum + 4);

  // ---- logits over col-tiles i=0,1 (cols 0..255)
  float w2v[2], b1v[2];
#pragma unroll
  for (int i = 0; i < 2; ++i) {
    int col = (wv + 8 * i) * 16 + q;
    w2v[i] = w2[col];
    b1v[i] = b1[col];
  }
#pragma unroll
  for (int rt = 0; rt < 4; ++rt) {
    float pr[4] = {0.f, 0.f, 0.f, 0.f};
#pragma unroll
    for (int i = 0; i < 2; ++i)
#pragma unroll
      for (int r = 0; r < 4; ++r)
        pr[r] += fmaxf(acc[i][rt][r] + b1v[i], 0.f) * w2v[i];
#pragma unroll
    for (int mk = 1; mk < 16; mk <<= 1)
#pragma unroll
      for (int r = 0; r < 4; ++r) pr[r] += __shfl_xor(pr[r], mk);
    if (q == 0)
#pragma unroll
      for (int r = 0; r < 4; ++r) lpart[wv * 64 + rt * 16 + p * 4 + r] = pr[r];
  }
  __syncthreads();

  bool nf = false;
  if (wv == 0) {
    float lg = b2[0];
#pragma unroll
    for (int w = 0; w < 8; ++w) lg += lpart[w * 64 + tid];
    llog[tid] = lg;
    nf = fabsf(lg - THRL) < FIX_MARGIN;
  }
  unsigned long long fm = __ballot(nf);
  if (tid == 0) *s_fixmask = fm;
  __syncthreads();

  // ---- exact fp32 recompute of borderline rows (rare)
  unsigned long long fixmask = *s_fixmask;
  while (fixmask) {
    int row = __ffsll(fixmask) - 1;
    fixmask &= fixmask - 1;
    if (tid < 256) {
      const float* prow = pf + (size_t)(m0 + row) * C_DIM;
      float a0 = 0.f, a1 = 0.f;
      for (int c = 0; c < C_DIM; c += 2) {
        a0 = fmaf(prow[c], w1[(size_t)c * H_DIM + tid], a0);
        a1 = fmaf(prow[c + 1], w1[(size_t)(c + 1) * H_DIM + tid], a1);
      }
      float v = fmaxf(a0 + a1 + b1[tid], 0.f) * w2[tid];
#pragma unroll
      for (int mk = 1; mk < 64; mk <<= 1) v += __shfl_xor(v, mk);
      if (lane == 0) fsum[wv] = v;
    }
    __syncthreads();
    if (tid == 0)
      llog[row] = fsum[0] + fsum[1] + fsum[2] + fsum[3] + b2[0];
    __syncthreads();
  }

  // ---- selection mask + aggregate + scores
  bool sel = false;
  float flog = 0.f;
  if (wv == 0) {
    flog = llog[tid];
    sel = flog > THRL;
  }
  unsigned long long selmask = __ballot(sel);
  if (wv == 0) {
    srow[tid] = 1.f / (1.f + expf(-flog));
    if (tid == 0) {
      tmask[tile] = selmask;
      tagg[tile] = __popcll(selmask);
    }
  }
  __syncthreads();

  // ---- scaled feature rows: G[m] = score*(pf@wo)+bo (col-tile i=2)
  {
    const int gcol = wv * 16 + q;
    const float bov = bo[gcol];
#pragma unroll
    for (int rt = 0; rt < 4; ++rt)
#pragma unroll
      for (int r = 0; r < 4; ++r) {
        int row = rt * 16 + p * 4 + r;
        G[(size_t)(m0 + row) * O_DIM + gcol] = fmaf(acc[2][rt][r], srow[row], bov);
      }
  }
}

// K2: per-batch exclusive scan of 256 tile aggregates. grid 8, block 256.
__global__ __launch_bounds__(256) void scan_tiles(const int* __restrict__ tagg,
                                                  int* __restrict__ texcl,
                                                  int* __restrict__ counts) {
  __shared__ int wsum[4];
  const int c = blockIdx.x, t = threadIdx.x;
  const int lane = t & 63, w = t >> 6;
  int v = tagg[c * 256 + t];
  int inc = v;
#pragma unroll
  for (int d = 1; d < 64; d <<= 1) {
    int n = __shfl_up(inc, d);
    if (lane >= d) inc += n;
  }
  if (lane == 63) wsum[w] = inc;
  __syncthreads();
  int base = 0;
#pragma unroll
  for (int ww = 0; ww < 4; ++ww)
    if (ww < w) base += wsum[ww];
  texcl[c * 256 + t] = base + inc - v;
  if (t == 255) counts[c] = base + inc;
}

// K3: compact selected rows. grid 2048, block 512 (wave wv: rows wv*8..+7)
__global__ __launch_bounds__(512) void scatter(
    const float* __restrict__ G, const unsigned long long* __restrict__ tmask,
    const int* __restrict__ texcl, const float* __restrict__ pc,
    float* __restrict__ out) {
  const int tile = blockIdx.x;
  const int tid = threadIdx.x;
  const int lane = tid & 63;
  const int wv = tid >> 6;
  const unsigned long long mask = tmask[tile];
  const int base = (tile >> 8) * N_PTS + texcl[tile];
  const int m0 = tile * TM;
#pragma unroll
  for (int j = 0; j < 8; ++j) {
    const int row = wv * 8 + j;
    if (!((mask >> row) & 1ull)) continue;
    const int dst = base + __popcll(mask & ((1ull << row) - 1ull));
    const int m = m0 + row;
    float2 g = *(const float2*)(G + (size_t)m * O_DIM + lane * 2);
    *(float2*)(out + (size_t)dst * O_DIM + lane * 2) = g;
    if (lane == 0) {
      float c0 = pc[m * 3], c1 = pc[m * 3 + 1], c2 = pc[m * 3 + 2];
      float* oc = out + OUT_COORD_OFF;
      oc[dst * 3] = c0; oc[dst * 3 + 1] = c1; oc[dst * 3 + 2] = c2;
      out[OUT_MASK_OFF + dst] = (c0 == 0.f || c1 == 0.f || c2 == 0.f) ? 1.f : 0.f;
    }
  }
}

// K4: zero-fill padding tail rows; mask=1 there. 2048 grid-stride blocks.
__global__ __launch_bounds__(256) void fill_tail(const int* __restrict__ counts,
                                                 float* __restrict__ out) {
  const int lane = threadIdx.x & 63;
  for (int m = blockIdx.x * 4 + (threadIdx.x >> 6); m < M_TOTAL; m += 8192) {
    int b = m >> 14, j = m & (N_PTS - 1);
    if (j < counts[b]) continue;
    *(float2*)(out + (size_t)m * O_DIM + lane * 2) = make_float2(0.f, 0.f);
    if (lane == 0) {
      float* oc = out + OUT_COORD_OFF;
      oc[m * 3] = 0.f; oc[m * 3 + 1] = 0.f; oc[m * 3 + 2] = 0.f;
      out[OUT_MASK_OFF + m] = 1.f;
    }
  }
}

extern "C" void kernel_launch(void* const* d_in, const int* in_sizes, int n_in,
                              void* d_out, int out_size, void* d_ws, size_t ws_size,
                              hipStream_t stream) {
  const float* pf = (const float*)d_in[0];
  const float* pc = (const float*)d_in[1];
  const float* w1 = (const float*)d_in[2];
  const float* b1 = (const float*)d_in[3];
  const float* w2 = (const float*)d_in[4];
  const float* b2 = (const float*)d_in[5];
  const float* wo = (const float*)d_in[6];
  const float* bo = (const float*)d_in[7];
  float* out = (float*)d_out;
  char* ws = (char*)d_ws;

  unsigned short* Wt2 = (unsigned short*)(ws + WT_OFF);
  unsigned long long* tmask = (unsigned long long*)(ws + TMASK_OFF);
  int* tagg = (int*)(ws + TAGG_OFF);
  int* texcl = (int*)(ws + TEXCL_OFF);
  int* counts = (int*)(ws + COUNTS_OFF);
  float* G = (float*)(ws + G_OFF);

  convert_w<<<960, 256, 0, stream>>>(w1, wo, Wt2);
  gemm_fused<<<NTILES, 512, 0, stream>>>(pf, Wt2, w1, b1, w2, b2, bo,
                                         tmask, tagg, G);
  scan_tiles<<<8, 256, 0, stream>>>(tagg, texcl, counts);
  scatter<<<NTILES, 512, 0, stream>>>(G, tmask, texcl, pc, out);
  fill_tail<<<2048, 256, 0, stream>>>(counts, out);
}

// Round 9
// 184.436 us; speedup vs baseline: 1.0702x; 1.0500x over previous
//
#include <hip/hip_runtime.h>
#include <hip/hip_bf16.h>

// ---------------------------------------------------------------------------
// KeypointWeighting R9: B-operand global->REGISTER (no B-LDS, no glds, no
// barrier-coupled vmem). A through a 3-deep 4KB LDS ring (8-way shared),
// one raw s_barrier + lgkmcnt(0) per K-step. B fragments are per-wave
// private (each col-tile owned by one wave) and pre-packed in Wt2 so each
// lane's 16B load is coalesced per wave.
// Pipeline: convert_w -> gemm -> scan -> scatter -> fill_tail.
// dims: B=8 N=16384 C=640 H=256 O=128, 2048 tiles of 64 rows.
// ---------------------------------------------------------------------------

typedef __attribute__((ext_vector_type(8))) short short8v;
typedef __attribute__((ext_vector_type(4))) float f32x4;

#define M_TOTAL 131072
#define C_DIM 640
#define H_DIM 256
#define O_DIM 128
#define NCOMB 384
#define TM 64
#define KSTEPS 20
#define N_PTS 16384
#define TILES_PER_B 256
#define NTILES 2048
#define THRL -0.4054651081f   // log(0.4/0.6)
#define FIX_MARGIN 0.03f

#define OUT_COORD_OFF 16777216
#define OUT_MASK_OFF  17170432

// ws layout (bytes)
#define WT_OFF     0u
#define TMASK_OFF  491520u     // u64 [2048]
#define TAGG_OFF   507904u     // i32 [2048]
#define TEXCL_OFF  516096u     // i32 [2048]
#define COUNTS_OFF 524288u     // i32 [8]
#define G_OFF      1572864u    // f32 [131072][128]

#define LGKMCNT0 asm volatile("s_waitcnt lgkmcnt(0)" ::: "memory")
#define SBAR __builtin_amdgcn_s_barrier()
#define SCHED0 __builtin_amdgcn_sched_barrier(0)

__device__ __forceinline__ unsigned int f2bf_bits(float f) {
  unsigned int u = __builtin_bit_cast(unsigned int, f);
  return (u + 0x7fffu + ((u >> 16) & 1u)) >> 16;
}
__device__ __forceinline__ unsigned int pack_bf2(float lo, float hi) {
  return f2bf_bits(lo) | (f2bf_bits(hi) << 16);
}

// K0: weights -> bf16, laid out so lane (q,p) of the wave owning col-tile ct
// loads its MFMA B-fragment for K-step t as ONE contiguous 16B:
//   elem offset = (((t*24 + ct)*16 + q)*4 + p)*8 + e
//   holds W[k = t*32 + p*8 + e][n = ct*16 + q]   (n<256 -> w1, else wo)
__global__ __launch_bounds__(256) void convert_w(const float* __restrict__ w1,
                                                 const float* __restrict__ wo,
                                                 unsigned short* __restrict__ Wt2) {
  int o = blockIdx.x * 256 + threadIdx.x;  // 960 x 256 = 245760
  if (o < NCOMB * C_DIM) {
    int e = o & 7;
    int g = o >> 3;           // granule 0..30719
    int pp = g & 3;
    int qq = (g >> 2) & 15;
    int tc = g >> 6;          // t*24 + ct
    int ct = tc % 24;
    int t = tc / 24;
    int k = t * 32 + pp * 8 + e;
    int n = ct * 16 + qq;
    float v = (n < H_DIM) ? w1[k * H_DIM + n] : wo[k * O_DIM + (n - H_DIM)];
    Wt2[o] = (unsigned short)f2bf_bits(v);
  }
}

// K1: GEMM (B in regs, A in 3-ring LDS) + scores (+fp32 fixup) + selmask + G.
__global__ __launch_bounds__(512, 4) void gemm_fused(
    const float* __restrict__ pf, const unsigned short* __restrict__ Wt2,
    const float* __restrict__ w1, const float* __restrict__ b1,
    const float* __restrict__ w2, const float* __restrict__ b2,
    const float* __restrict__ bo, unsigned long long* __restrict__ tmask,
    int* __restrict__ tagg, float* __restrict__ G) {
  __shared__ __align__(16) unsigned short As[3][2048];  // 3 x 4 KB A ring

  const int tid = threadIdx.x;
  const int lane = tid & 63;
  const int wv = tid >> 6;
  const int q = lane & 15;
  const int p = lane >> 4;
  const int tile = blockIdx.x;
  const int m0 = tile * TM;

  f32x4 acc[3][4];
#pragma unroll
  for (int i = 0; i < 3; ++i)
#pragma unroll
    for (int rt = 0; rt < 4; ++rt) acc[i][rt] = (f32x4){0.f, 0.f, 0.f, 0.f};

  // A staging (R5-verified): lane loads pf[row=tid>>3][ (tid&7)*4 ..+4 ],
  // writes 8B bf16 to swizzled granule; reads 16B frags with matching swizzle.
  const float* asrc = pf + (size_t)(m0 + (tid >> 3)) * C_DIM + (tid & 7) * 4;
  const int aphys = ((tid >> 1) ^ ((tid >> 4) & 3)) * 8 + (tid & 1) * 4;
  const int aswz = (q >> 1) & 3;

  // B per-lane base: ct = wv + 8i; elem off = ct*512 + q*32 + p*8 (+ t*12288)
  const unsigned short* bbase = Wt2 + wv * 512 + q * 32 + p * 8;

  // ---- prologue: A(0) staged; pf(1) in regs; B(0) in regs
  float4 Rcur;
  short8v bc0, bc1, bc2;
  {
    float4 R0 = *(const float4*)(asrc);
    bc0 = *(const short8v*)(bbase);
    bc1 = *(const short8v*)(bbase + 4096);
    bc2 = *(const short8v*)(bbase + 8192);
    Rcur = *(const float4*)(asrc + 32);
    *(uint2*)&As[0][aphys] = make_uint2(pack_bf2(R0.x, R0.y), pack_bf2(R0.z, R0.w));
    LGKMCNT0;
    SCHED0;
    SBAR;
  }

  // ---- main loop: 1 barrier/step; vmem never barrier-coupled
#pragma unroll
  for (int t = 0; t < KSTEPS; ++t) {
    float4 Rnext;
    short8v bn0, bn1, bn2;
    if (t + 2 < KSTEPS) Rnext = *(const float4*)(asrc + (t + 2) * 32);
    if (t + 1 < KSTEPS) {
      const unsigned short* bp = bbase + (size_t)(t + 1) * 12288;
      bn0 = *(const short8v*)(bp);
      bn1 = *(const short8v*)(bp + 4096);
      bn2 = *(const short8v*)(bp + 8192);
      // cvt pf(t+1) -> A ring slot (t+1)%3 (readers of this slot finished
      // before barrier(t-1); ring-3 makes the 1-barrier schedule WAR-safe)
      *(uint2*)&As[(t + 1) % 3][aphys] =
          make_uint2(pack_bf2(Rcur.x, Rcur.y), pack_bf2(Rcur.z, Rcur.w));
      Rcur = Rnext;
    }
    LGKMCNT0;   // my ds_write (and prior ds_reads) drained before signaling
    SCHED0;
    SBAR;
    // read A(t) frags, MFMA with B(t) regs (compiler emits counted vmcnt)
    short8v af[4];
#pragma unroll
    for (int rt = 0; rt < 4; ++rt)
      af[rt] = *(const short8v*)&As[t % 3][((rt * 64 + q * 4 + p) ^ aswz) * 8];
    __builtin_amdgcn_s_setprio(1);
#pragma unroll
    for (int rt = 0; rt < 4; ++rt) {
      acc[0][rt] = __builtin_amdgcn_mfma_f32_16x16x32_bf16(af[rt], bc0, acc[0][rt], 0, 0, 0);
      acc[1][rt] = __builtin_amdgcn_mfma_f32_16x16x32_bf16(af[rt], bc1, acc[1][rt], 0, 0, 0);
      acc[2][rt] = __builtin_amdgcn_mfma_f32_16x16x32_bf16(af[rt], bc2, acc[2][rt], 0, 0, 0);
    }
    __builtin_amdgcn_s_setprio(0);
    bc0 = bn0; bc1 = bn1; bc2 = bn2;
  }
  __syncthreads();  // full drain; A ring becomes epilogue scratch

  // epilogue scratch aliases (12 KB available)
  float* lpart = (float*)&As[0][0];                 // [8][64] = 2 KB
  float* llog = (float*)&As[1][0];                  // 64
  float* srow = llog + 64;                          // 64
  float* fsum = srow + 64;                          // 4
  unsigned long long* s_fixmask = (unsigned long long*)(fsum + 4);

  // ---- logits over col-tiles i=0,1 (cols 0..255): col = (wv+8i)*16+q
  float w2v[2], b1v[2];
#pragma unroll
  for (int i = 0; i < 2; ++i) {
    int col = (wv + 8 * i) * 16 + q;
    w2v[i] = w2[col];
    b1v[i] = b1[col];
  }
#pragma unroll
  for (int rt = 0; rt < 4; ++rt) {
    float pr[4] = {0.f, 0.f, 0.f, 0.f};
#pragma unroll
    for (int i = 0; i < 2; ++i)
#pragma unroll
      for (int r = 0; r < 4; ++r)
        pr[r] += fmaxf(acc[i][rt][r] + b1v[i], 0.f) * w2v[i];
#pragma unroll
    for (int mk = 1; mk < 16; mk <<= 1)
#pragma unroll
      for (int r = 0; r < 4; ++r) pr[r] += __shfl_xor(pr[r], mk);
    if (q == 0)
#pragma unroll
      for (int r = 0; r < 4; ++r) lpart[wv * 64 + rt * 16 + p * 4 + r] = pr[r];
  }
  __syncthreads();

  bool nf = false;
  if (wv == 0) {
    float lg = b2[0];
#pragma unroll
    for (int w = 0; w < 8; ++w) lg += lpart[w * 64 + tid];
    llog[tid] = lg;
    nf = fabsf(lg - THRL) < FIX_MARGIN;
  }
  unsigned long long fm = __ballot(nf);
  if (tid == 0) *s_fixmask = fm;
  __syncthreads();

  // ---- exact fp32 recompute of borderline rows (rare)
  unsigned long long fixmask = *s_fixmask;
  while (fixmask) {
    int row = __ffsll(fixmask) - 1;
    fixmask &= fixmask - 1;
    if (tid < 256) {
      const float* prow = pf + (size_t)(m0 + row) * C_DIM;
      float a0 = 0.f, a1 = 0.f;
      for (int c = 0; c < C_DIM; c += 2) {
        a0 = fmaf(prow[c], w1[(size_t)c * H_DIM + tid], a0);
        a1 = fmaf(prow[c + 1], w1[(size_t)(c + 1) * H_DIM + tid], a1);
      }
      float v = fmaxf(a0 + a1 + b1[tid], 0.f) * w2[tid];
#pragma unroll
      for (int mk = 1; mk < 64; mk <<= 1) v += __shfl_xor(v, mk);
      if (lane == 0) fsum[wv] = v;
    }
    __syncthreads();
    if (tid == 0)
      llog[row] = fsum[0] + fsum[1] + fsum[2] + fsum[3] + b2[0];
    __syncthreads();
  }

  // ---- selection mask + aggregate + scores
  bool sel = false;
  float flog = 0.f;
  if (wv == 0) {
    flog = llog[tid];
    sel = flog > THRL;
  }
  unsigned long long selmask = __ballot(sel);
  if (wv == 0) {
    srow[tid] = 1.f / (1.f + expf(-flog));
    if (tid == 0) {
      tmask[tile] = selmask;
      tagg[tile] = __popcll(selmask);
    }
  }
  __syncthreads();

  // ---- scaled feature rows: G[m] = score*(pf@wo)+bo (col-tile i=2, ct=wv+16)
  {
    const int gcol = wv * 16 + q;
    const float bov = bo[gcol];
#pragma unroll
    for (int rt = 0; rt < 4; ++rt)
#pragma unroll
      for (int r = 0; r < 4; ++r) {
        int row = rt * 16 + p * 4 + r;
        G[(size_t)(m0 + row) * O_DIM + gcol] = fmaf(acc[2][rt][r], srow[row], bov);
      }
  }
}

// K2: per-batch exclusive scan of 256 tile aggregates. grid 8, block 256.
__global__ __launch_bounds__(256) void scan_tiles(const int* __restrict__ tagg,
                                                  int* __restrict__ texcl,
                                                  int* __restrict__ counts) {
  __shared__ int wsum[4];
  const int c = blockIdx.x, t = threadIdx.x;
  const int lane = t & 63, w = t >> 6;
  int v = tagg[c * 256 + t];
  int inc = v;
#pragma unroll
  for (int d = 1; d < 64; d <<= 1) {
    int n = __shfl_up(inc, d);
    if (lane >= d) inc += n;
  }
  if (lane == 63) wsum[w] = inc;
  __syncthreads();
  int base = 0;
#pragma unroll
  for (int ww = 0; ww < 4; ++ww)
    if (ww < w) base += wsum[ww];
  texcl[c * 256 + t] = base + inc - v;
  if (t == 255) counts[c] = base + inc;
}

// K3: compact selected rows. grid 2048, block 512 (wave wv: rows wv*8..+7)
__global__ __launch_bounds__(512) void scatter(
    const float* __restrict__ G, const unsigned long long* __restrict__ tmask,
    const int* __restrict__ texcl, const float* __restrict__ pc,
    float* __restrict__ out) {
  const int tile = blockIdx.x;
  const int tid = threadIdx.x;
  const int lane = tid & 63;
  const int wv = tid >> 6;
  const unsigned long long mask = tmask[tile];
  const int base = (tile >> 8) * N_PTS + texcl[tile];
  const int m0 = tile * TM;
#pragma unroll
  for (int j = 0; j < 8; ++j) {
    const int row = wv * 8 + j;
    if (!((mask >> row) & 1ull)) continue;
    const int dst = base + __popcll(mask & ((1ull << row) - 1ull));
    const int m = m0 + row;
    float2 g = *(const float2*)(G + (size_t)m * O_DIM + lane * 2);
    *(float2*)(out + (size_t)dst * O_DIM + lane * 2) = g;
    if (lane == 0) {
      float c0 = pc[m * 3], c1 = pc[m * 3 + 1], c2 = pc[m * 3 + 2];
      float* oc = out + OUT_COORD_OFF;
      oc[dst * 3] = c0; oc[dst * 3 + 1] = c1; oc[dst * 3 + 2] = c2;
      out[OUT_MASK_OFF + dst] = (c0 == 0.f || c1 == 0.f || c2 == 0.f) ? 1.f : 0.f;
    }
  }
}

// K4: zero-fill padding tail rows; mask=1 there. 2048 grid-stride blocks.
__global__ __launch_bounds__(256) void fill_tail(const int* __restrict__ counts,
                                                 float* __restrict__ out) {
  const int lane = threadIdx.x & 63;
  for (int m = blockIdx.x * 4 + (threadIdx.x >> 6); m < M_TOTAL; m += 8192) {
    int b = m >> 14, j = m & (N_PTS - 1);
    if (j < counts[b]) continue;
    *(float2*)(out + (size_t)m * O_DIM + lane * 2) = make_float2(0.f, 0.f);
    if (lane == 0) {
      float* oc = out + OUT_COORD_OFF;
      oc[m * 3] = 0.f; oc[m * 3 + 1] = 0.f; oc[m * 3 + 2] = 0.f;
      out[OUT_MASK_OFF + m] = 1.f;
    }
  }
}

extern "C" void kernel_launch(void* const* d_in, const int* in_sizes, int n_in,
                              void* d_out, int out_size, void* d_ws, size_t ws_size,
                              hipStream_t stream) {
  const float* pf = (const float*)d_in[0];
  const float* pc = (const float*)d_in[1];
  const float* w1 = (const float*)d_in[2];
  const float* b1 = (const float*)d_in[3];
  const float* w2 = (const float*)d_in[4];
  const float* b2 = (const float*)d_in[5];
  const float* wo = (const float*)d_in[6];
  const float* bo = (const float*)d_in[7];
  float* out = (float*)d_out;
  char* ws = (char*)d_ws;

  unsigned short* Wt2 = (unsigned short*)(ws + WT_OFF);
  unsigned long long* tmask = (unsigned long long*)(ws + TMASK_OFF);
  int* tagg = (int*)(ws + TAGG_OFF);
  int* texcl = (int*)(ws + TEXCL_OFF);
  int* counts = (int*)(ws + COUNTS_OFF);
  float* G = (float*)(ws + G_OFF);

  convert_w<<<960, 256, 0, stream>>>(w1, wo, Wt2);
  gemm_fused<<<NTILES, 512, 0, stream>>>(pf, Wt2, w1, b1, w2, b2, bo,
                                         tmask, tagg, G);
  scan_tiles<<<8, 256, 0, stream>>>(tagg, texcl, counts);
  scatter<<<NTILES, 512, 0, stream>>>(G, tmask, texcl, pc, out);
  fill_tail<<<2048, 256, 0, stream>>>(counts, out);
}